// Round 1
// 494.957 us; speedup vs baseline: 1.1450x; 1.1450x over previous
//
#include <hip/hip_runtime.h>
#include <hip/hip_bf16.h>
#include <math.h>

// ---------------------------------------------------------------------------
// QuantumProcessingLayer: out = tanh(concat(f(x), f(x)^2) @ W + b)
//   f(x) = tanh(2pi x) + 0.1*sin(2pi x)*cos(pi x)
// M=16384 (B*S), F=2048, K=4096 (2F), N=2048 (U). fp32 in/out, bf16 MFMA core.
// R4: 256x256-tile, 8-phase K-loop with COUNTED vmcnt (T3+T4), setprio around
//     MFMA clusters (T5), XCD block swizzle (T1). LDS = 4 rotating 16KB slots
//     per operand (k-half granularity), 128 KiB total, 1 block/CU, 8 waves.
//     Schedule invariants (per-wave vmcnt queue, 2 loads per half-tile):
//       prologue: A0 B0 A1 B1 | vmcnt(4) | A2 B2 B3 | vmcnt(6) | barrier
//       tile h (4 phases): ph1 stages A(h+3), ph2 B(h+4), ph3 A(h+4),
//       ph4 B(h+5); end-of-tile vmcnt(6) leaves exactly {B(h+4),A(h+4),
//       B(h+5)} in flight and guarantees tile h+2's operands. Targets are
//       always slots whose reads completed before the issuing phase's open.
// ---------------------------------------------------------------------------

typedef __bf16 b16x8 __attribute__((ext_vector_type(8)));
typedef float f32x4 __attribute__((ext_vector_type(4)));

constexpr int Mdim = 16384;
constexpr int Fdim = 2048;
constexpr int Kdim = 4096;
constexpr int Ndim = 2048;

// tanh(2*pi*x): e = exp(-4*pi*|x|); t = (1-e)/(1+e) via v_rcp
__device__ __forceinline__ float tanh_2pix(float x) {
  float ax = fabsf(x);
  float e = __expf(-12.566370614359172f * ax);
  float t = (1.0f - e) * __builtin_amdgcn_rcpf(1.0f + e);
  return copysignf(t, x);
}

__device__ __forceinline__ float fast_tanh(float x) {
  float ax = fabsf(x);
  float e = __expf(-2.0f * ax);
  float t = (1.0f - e) * __builtin_amdgcn_rcpf(1.0f + e);
  return copysignf(t, x);
}

// ---------------- prologue: feats[m][k] (bf16), k<F: qe, k>=F: qe^2 ---------
struct __align__(16) B8 { __bf16 v[8]; };

__global__ void feats_kernel(const float* __restrict__ x, __bf16* __restrict__ feats) {
  int idx = blockIdx.x * blockDim.x + threadIdx.x;  // one thread per 8 elems
  long i8 = (long)idx << 3;
  float4 xv0 = reinterpret_cast<const float4*>(x)[idx * 2];
  float4 xv1 = reinterpret_cast<const float4*>(x)[idx * 2 + 1];
  float q[8] = {xv0.x, xv0.y, xv0.z, xv0.w, xv1.x, xv1.y, xv1.z, xv1.w};
  B8 qe, en;
#pragma unroll
  for (int j = 0; j < 8; ++j) {
    float xx = q[j];
    // sin(2*pi*x) = v_sin(x revolutions); cos(pi*x) = v_cos(x/2 revolutions)
    float s = __builtin_amdgcn_sinf(xx);
    float c = __builtin_amdgcn_cosf(0.5f * xx);
    float v = tanh_2pix(xx) + 0.1f * s * c;
    qe.v[j] = (__bf16)v;
    en.v[j] = (__bf16)(v * v);
  }
  int m = (int)(i8 >> 11);     // / Fdim
  int f = (int)(i8 & (Fdim - 1));
  size_t base = (size_t)m * Kdim + f;
  *reinterpret_cast<B8*>(feats + base) = qe;
  *reinterpret_cast<B8*>(feats + base + Fdim) = en;
}

// ---------------- W [K][N] fp32  ->  Wt [N][K] bf16 ------------------------
__global__ void wtrans_kernel(const float* __restrict__ W, __bf16* __restrict__ Wt) {
  __shared__ float tile[32][33];
  int bn = blockIdx.x;   // N/32 = 64
  int bk = blockIdx.y;   // K/32 = 128
  int tx = threadIdx.x;  // 0..31
  int ty = threadIdx.y;  // 0..7
#pragma unroll
  for (int i = 0; i < 4; ++i) {
    int kk = bk * 32 + ty + i * 8;
    tile[ty + i * 8][tx] = W[(size_t)kk * Ndim + bn * 32 + tx];
  }
  __syncthreads();
#pragma unroll
  for (int i = 0; i < 4; ++i) {
    int nn = bn * 32 + ty + i * 8;
    Wt[(size_t)nn * Kdim + bk * 32 + tx] = (__bf16)tile[tx][ty + i * 8];
  }
}

// ---------------- GEMM: out = tanh(A @ Wt^T + b), 8-phase schedule ----------
typedef const __attribute__((address_space(1))) void* gptr1;
typedef __attribute__((address_space(3))) void* lptr3;

__device__ __forceinline__ void gld_lds16(const __bf16* g, __bf16* l) {
  __builtin_amdgcn_global_load_lds((gptr1)g, (lptr3)l, 16, 0, 0);
}

#define BARRIER()    asm volatile("s_barrier" ::: "memory")
#define WAIT_LGKM0() asm volatile("s_waitcnt lgkmcnt(0)" ::: "memory")
#define WAIT_VM(n)   asm volatile("s_waitcnt vmcnt(" #n ")" ::: "memory")

// One K-tile = 2 k-halves of 32. 4 phases; S1..S4 select which prefetches run.
// Phase = {ds_read frag subtile; issue 1 half-tile prefetch; barrier;
//          lgkmcnt(0); setprio(1); 16 MFMA; setprio(0); barrier}.
// Caller appends the per-tile vmcnt + closing barrier.
#define TILE(h, S1, S2, S3, S4) do {                                        \
    const int s0_ = (h) & 3, s1_ = ((h) + 1) & 3;                           \
    rdA(s0_, 0); rdB(s0_);                                                  \
    if (S1) stageA((h) + 3);                                                \
    BARRIER(); WAIT_LGKM0();                                                \
    mfma4(0);                                                               \
    BARRIER();                                                              \
    rdA(s0_, 4);                                                            \
    if (S2) stageB((h) + 4);                                                \
    BARRIER(); WAIT_LGKM0();                                                \
    mfma4(4);                                                               \
    BARRIER();                                                              \
    rdA(s1_, 0); rdB(s1_);                                                  \
    if (S3) stageA((h) + 4);                                                \
    BARRIER(); WAIT_LGKM0();                                                \
    mfma4(0);                                                               \
    BARRIER();                                                              \
    rdA(s1_, 4);                                                            \
    if (S4) stageB((h) + 5);                                                \
    BARRIER(); WAIT_LGKM0();                                                \
    mfma4(4);                                                               \
  } while (0)

__global__ __launch_bounds__(512, 2) void gemm_tanh_kernel(
    const __bf16* __restrict__ A,    // [M][K] feats
    const __bf16* __restrict__ Bt,   // [N][K] W^T
    const float* __restrict__ bias,  // [N]
    float* __restrict__ out) {       // [M][N]
  // 128 KiB: A slots [4][256 rows][32 k] then B slots [4][256][32]
  __shared__ __align__(16) __bf16 smem[65536];
  __bf16* const sA = smem;           // 4 x 8192 elems
  __bf16* const sB = smem + 32768;   // 4 x 8192 elems

  const int tid = threadIdx.x;
  const int wv = tid >> 6;
  const int lane = tid & 63;

  // T1: XCD-aware bijective swizzle (nwg=512, 512%8==0). Each XCD gets 64
  // consecutive wg = 8 M-tiles x 8 N-tiles -> A-panel L2 reuse.
  const int orig = blockIdx.y * 8 + blockIdx.x;
  const int wg = (orig & 7) * 64 + (orig >> 3);
  const int m0 = (wg >> 3) * 256;
  const int n0 = (wg & 7) * 256;

  const int wm = (wv >> 2) * 128;  // 2 M-waves
  const int wn = (wv & 3) * 64;    // 4 N-waves
  const int lr = lane & 15;
  const int lq = lane >> 4;

  // ---- staging: half-tile = one slot (256 rows x 32 k = 16 KB).
  // 16B chunk L = wv*128 + l*64 + lane; LDS linear (row = L>>2, pos = L&3);
  // pre-swizzled global source chunk kq = (L&3) ^ ((row>>1)&3) so the read
  // side's proven XOR pattern (0 bank conflicts in R2/R3) sees its data.
  const int L0 = wv * 128 + lane;
  const int L1 = L0 + 64;
  const int r0 = L0 >> 2, r1 = L1 >> 2;
  const int c0 = (L0 & 3) ^ ((r0 >> 1) & 3);
  const int c1 = (L1 & 3) ^ ((r1 >> 1) & 3);
  const __bf16* gA0 = A + (size_t)(m0 + r0) * Kdim + c0 * 8;
  const __bf16* gA1 = A + (size_t)(m0 + r1) * Kdim + c1 * 8;
  const __bf16* gB0 = Bt + (size_t)(n0 + r0) * Kdim + c0 * 8;
  const __bf16* gB1 = Bt + (size_t)(n0 + r1) * Kdim + c1 * 8;
  const int d0 = wv * 1024;        // wave-uniform LDS dest (HW adds lane*16B)
  const int d1 = d0 + 512;

  auto stageA = [&](int h) {
    __bf16* s = sA + (h & 3) * 8192;
    gld_lds16(gA0 + h * 32, s + d0);
    gld_lds16(gA1 + h * 32, s + d1);
  };
  auto stageB = [&](int h) {
    __bf16* s = sB + (h & 3) * 8192;
    gld_lds16(gB0 + h * 32, s + d0);
    gld_lds16(gB1 + h * 32, s + d1);
  };

  // ---- fragment reads (swizzled chunk, identical pattern to R3: 0 conflicts)
  const int chunk = (lq ^ ((lr >> 1) & 3)) * 8;
  const int ard = (wm + lr) * 32 + chunk;
  const int brd = (wn + lr) * 32 + chunk;

  f32x4 acc[8][4];
#pragma unroll
  for (int i = 0; i < 8; ++i)
#pragma unroll
    for (int j = 0; j < 4; ++j) acc[i][j] = (f32x4){0.f, 0.f, 0.f, 0.f};

  b16x8 av[4], bv[4];
  auto rdA = [&](int s, int fb) {
#pragma unroll
    for (int i = 0; i < 4; ++i)
      av[i] = *reinterpret_cast<const b16x8*>(sA + s * 8192 + ard + (fb + i) * 512);
  };
  auto rdB = [&](int s) {
#pragma unroll
    for (int i = 0; i < 4; ++i)
      bv[i] = *reinterpret_cast<const b16x8*>(sB + s * 8192 + brd + i * 512);
  };
  auto mfma4 = [&](int fb) {
    __builtin_amdgcn_s_setprio(1);
#pragma unroll
    for (int i = 0; i < 4; ++i)
#pragma unroll
      for (int j = 0; j < 4; ++j)
        acc[fb + i][j] =
            __builtin_amdgcn_mfma_f32_16x16x32_bf16(av[i], bv[j], acc[fb + i][j], 0, 0, 0);
    __builtin_amdgcn_s_setprio(0);
  };

  // Bias loaded & drained BEFORE staging: a stray VMEM op inside the loop
  // would shift the hand-counted vmcnt queue and break the schedule.
  float bval[4];
#pragma unroll
  for (int j = 0; j < 4; ++j) bval[j] = bias[n0 + wn + j * 16 + lr];
  WAIT_VM(0);

  // ---- prologue: 4 halves, wait(4), 3 more halves, wait(6) -----------------
  stageA(0); stageB(0); stageA(1); stageB(1);
  WAIT_VM(4);
  stageA(2); stageB(2); stageB(3);
  WAIT_VM(6);
  BARRIER();

  // ---- main loop: 31 iterations x 2 K-tiles (8 phases), tiles h=0..122 ----
  for (int u = 0; u < 31; ++u) {
    const int h = u * 4;
    TILE(h, 1, 1, 1, 1);
    WAIT_VM(6); BARRIER();
    TILE(h + 2, 1, 1, 1, 1);
    WAIT_VM(6); BARRIER();
  }
  // ---- tail: tile 62 stages only A(127); drain; tile 63 stages nothing ----
  TILE(124, 1, 0, 0, 0);
  WAIT_VM(0); BARRIER();
  TILE(126, 0, 0, 0, 0);

  // ---- epilogue: C/D layout col=lane&15, row=(lane>>4)*4+reg --------------
#pragma unroll
  for (int j = 0; j < 4; ++j) {
    const int gn = n0 + wn + j * 16 + lr;
#pragma unroll
    for (int i = 0; i < 8; ++i) {
      const int gm = m0 + wm + i * 16 + lq * 4;
#pragma unroll
      for (int r = 0; r < 4; ++r) {
        float v = acc[i][j][r] + bval[j];
        out[(size_t)(gm + r) * Ndim + gn] = fast_tanh(v);
      }
    }
  }
}

// ---------------------------------------------------------------------------
extern "C" void kernel_launch(void* const* d_in, const int* in_sizes, int n_in,
                              void* d_out, int out_size, void* d_ws, size_t ws_size,
                              hipStream_t stream) {
  const float* x = (const float*)d_in[0];
  const float* W = (const float*)d_in[1];
  const float* b = (const float*)d_in[2];
  float* out = (float*)d_out;

  // ws layout: Wt bf16 [N*K] (16.8 MB) | feats bf16 [M*K] (134 MB)
  __bf16* Wt = (__bf16*)d_ws;
  __bf16* feats = Wt + (size_t)Ndim * Kdim;

  hipLaunchKernelGGL(feats_kernel, dim3(Mdim * Fdim / 8 / 256), dim3(256), 0,
                     stream, x, feats);
  hipLaunchKernelGGL(wtrans_kernel, dim3(Ndim / 32, Kdim / 32), dim3(32, 8), 0,
                     stream, W, Wt);
  hipLaunchKernelGGL(gemm_tanh_kernel, dim3(Ndim / 256, Mdim / 256), dim3(512),
                     0, stream, feats, Wt, b, out);
}

// Round 2
// 487.930 us; speedup vs baseline: 1.1615x; 1.0144x over previous
//
#include <hip/hip_runtime.h>
#include <hip/hip_bf16.h>
#include <math.h>

// ---------------------------------------------------------------------------
// QuantumProcessingLayer: out = tanh(concat(f(x), f(x)^2) @ W + b)
//   f(x) = tanh(2pi x) + 0.1*sin(2pi x)*cos(pi x)
// M=16384 (B*S), F=2048, K=4096 (2F), N=2048 (U). fp32 in/out, bf16 MFMA core.
// R5: single-barrier phases + one-cluster-ahead register prefetch.
//     Phase = {lgkmcnt(0); [vmcnt(N)]; barrier; stage-issue; 16 MFMA on regs
//     prefetched last phase; issue next cluster's ds_reads}. 4 barriers/tile
//     (was 9); frag-read latency hides under the MFMA cluster.
//     vmcnt queue (2 gld per stage, per wave), re-simulated for the new wait
//     points: prologue leaves {A2,B2,B3}=6 in flight; steady tile h issues
//     A(h+3),B(h+4),A(h+4),B(h+5); ph2 vmcnt(6) lands A(h+1),B(h+2) and
//     ph4 vmcnt(6) lands A(h+2),B(h+3) -- exactly what the reads issued in
//     those phases need. Tail: vmcnt(6)/vmcnt(4)/vmcnt(0) peel.
//     Stage-issue is always preceded by lgkmcnt(0)+barrier in every wave, so
//     zero ds_reads are in flight block-wide when a slot is overwritten.
// ---------------------------------------------------------------------------

typedef __bf16 b16x8 __attribute__((ext_vector_type(8)));
typedef float f32x4 __attribute__((ext_vector_type(4)));

constexpr int Mdim = 16384;
constexpr int Fdim = 2048;
constexpr int Kdim = 4096;
constexpr int Ndim = 2048;

// tanh(2*pi*x): e = exp(-4*pi*|x|); t = (1-e)/(1+e) via v_rcp
__device__ __forceinline__ float tanh_2pix(float x) {
  float ax = fabsf(x);
  float e = __expf(-12.566370614359172f * ax);
  float t = (1.0f - e) * __builtin_amdgcn_rcpf(1.0f + e);
  return copysignf(t, x);
}

__device__ __forceinline__ float fast_tanh(float x) {
  float ax = fabsf(x);
  float e = __expf(-2.0f * ax);
  float t = (1.0f - e) * __builtin_amdgcn_rcpf(1.0f + e);
  return copysignf(t, x);
}

// ---------------- prologue: feats[m][k] (bf16), k<F: qe, k>=F: qe^2 ---------
struct __align__(16) B8 { __bf16 v[8]; };

__global__ void feats_kernel(const float* __restrict__ x, __bf16* __restrict__ feats) {
  int idx = blockIdx.x * blockDim.x + threadIdx.x;  // one thread per 8 elems
  long i8 = (long)idx << 3;
  float4 xv0 = reinterpret_cast<const float4*>(x)[idx * 2];
  float4 xv1 = reinterpret_cast<const float4*>(x)[idx * 2 + 1];
  float q[8] = {xv0.x, xv0.y, xv0.z, xv0.w, xv1.x, xv1.y, xv1.z, xv1.w};
  B8 qe, en;
#pragma unroll
  for (int j = 0; j < 8; ++j) {
    float xx = q[j];
    // sin(2*pi*x) = v_sin(x revolutions); cos(pi*x) = v_cos(x/2 revolutions)
    float s = __builtin_amdgcn_sinf(xx);
    float c = __builtin_amdgcn_cosf(0.5f * xx);
    float v = tanh_2pix(xx) + 0.1f * s * c;
    qe.v[j] = (__bf16)v;
    en.v[j] = (__bf16)(v * v);
  }
  int m = (int)(i8 >> 11);     // / Fdim
  int f = (int)(i8 & (Fdim - 1));
  size_t base = (size_t)m * Kdim + f;
  *reinterpret_cast<B8*>(feats + base) = qe;
  *reinterpret_cast<B8*>(feats + base + Fdim) = en;
}

// ---------------- W [K][N] fp32  ->  Wt [N][K] bf16 ------------------------
__global__ void wtrans_kernel(const float* __restrict__ W, __bf16* __restrict__ Wt) {
  __shared__ float tile[32][33];
  int bn = blockIdx.x;   // N/32 = 64
  int bk = blockIdx.y;   // K/32 = 128
  int tx = threadIdx.x;  // 0..31
  int ty = threadIdx.y;  // 0..7
#pragma unroll
  for (int i = 0; i < 4; ++i) {
    int kk = bk * 32 + ty + i * 8;
    tile[ty + i * 8][tx] = W[(size_t)kk * Ndim + bn * 32 + tx];
  }
  __syncthreads();
#pragma unroll
  for (int i = 0; i < 4; ++i) {
    int nn = bn * 32 + ty + i * 8;
    Wt[(size_t)nn * Kdim + bk * 32 + tx] = (__bf16)tile[tx][ty + i * 8];
  }
}

// ---------------- GEMM: out = tanh(A @ Wt^T + b) ---------------------------
typedef const __attribute__((address_space(1))) void* gptr1;
typedef __attribute__((address_space(3))) void* lptr3;

__device__ __forceinline__ void gld_lds16(const __bf16* g, __bf16* l) {
  __builtin_amdgcn_global_load_lds((gptr1)g, (lptr3)l, 16, 0, 0);
}

#define BARRIER()    asm volatile("s_barrier" ::: "memory")
#define WAIT_LGKM0() asm volatile("s_waitcnt lgkmcnt(0)" ::: "memory")
#define WAIT_VM(n)   asm volatile("s_waitcnt vmcnt(" #n ")" ::: "memory")

// MFMA cluster: 16 x 16x16x32 on acc rows [FB..FB+3]. av/bv were prefetched
// during the previous phase; correctness of the lgkm wait is also enforced by
// the compiler's own dependency tracking (loads are compiler-visible).
#define MFMA16(AV, BV, FB) do {                                               \
    __builtin_amdgcn_s_setprio(1);                                            \
    _Pragma("unroll")                                                         \
    for (int i_ = 0; i_ < 4; ++i_)                                            \
      _Pragma("unroll")                                                       \
      for (int j_ = 0; j_ < 4; ++j_)                                          \
        acc[(FB) + i_][j_] = __builtin_amdgcn_mfma_f32_16x16x32_bf16(         \
            AV[i_], BV[j_], acc[(FB) + i_][j_], 0, 0, 0);                     \
    __builtin_amdgcn_s_setprio(0);                                            \
  } while (0)

__global__ __launch_bounds__(512, 2) void gemm_tanh_kernel(
    const __bf16* __restrict__ A,    // [M][K] feats
    const __bf16* __restrict__ Bt,   // [N][K] W^T
    const float* __restrict__ bias,  // [N]
    float* __restrict__ out) {       // [M][N]
  // 128 KiB: A slots [4][256 rows][32 k] then B slots [4][256][32]
  __shared__ __align__(16) __bf16 smem[65536];
  __bf16* const sA = smem;           // 4 x 8192 elems
  __bf16* const sB = smem + 32768;   // 4 x 8192 elems

  const int tid = threadIdx.x;
  const int wv = tid >> 6;
  const int lane = tid & 63;

  // T1: XCD-aware bijective swizzle (nwg=512, 512%8==0). Each XCD gets 64
  // consecutive wg = 8 M-tiles x 8 N-tiles -> A-panel L2 reuse.
  const int orig = blockIdx.y * 8 + blockIdx.x;
  const int wg = (orig & 7) * 64 + (orig >> 3);
  const int m0 = (wg >> 3) * 256;
  const int n0 = (wg & 7) * 256;

  const int wm = (wv >> 2) * 128;  // 2 M-waves
  const int wn = (wv & 3) * 64;    // 4 N-waves
  const int lr = lane & 15;
  const int lq = lane >> 4;

  // ---- staging: half-tile = one slot (256 rows x 32 k = 16 KB).
  // 16B chunk L = wv*128 + l*64 + lane; LDS linear (row = L>>2, pos = L&3);
  // pre-swizzled global source chunk kq = (L&3) ^ ((row>>1)&3) so the read
  // side's proven XOR pattern (0 bank conflicts R2-R4) sees its data.
  const int L0 = wv * 128 + lane;
  const int L1 = L0 + 64;
  const int r0 = L0 >> 2, r1 = L1 >> 2;
  const int c0 = (L0 & 3) ^ ((r0 >> 1) & 3);
  const int c1 = (L1 & 3) ^ ((r1 >> 1) & 3);
  const __bf16* gA0 = A + (size_t)(m0 + r0) * Kdim + c0 * 8;
  const __bf16* gA1 = A + (size_t)(m0 + r1) * Kdim + c1 * 8;
  const __bf16* gB0 = Bt + (size_t)(n0 + r0) * Kdim + c0 * 8;
  const __bf16* gB1 = Bt + (size_t)(n0 + r1) * Kdim + c1 * 8;
  const int d0 = wv * 1024;        // wave-uniform LDS dest (HW adds lane*16B)
  const int d1 = d0 + 512;

  auto stageA = [&](int h) {
    __bf16* s = sA + (h & 3) * 8192;
    gld_lds16(gA0 + h * 32, s + d0);
    gld_lds16(gA1 + h * 32, s + d1);
  };
  auto stageB = [&](int h) {
    __bf16* s = sB + (h & 3) * 8192;
    gld_lds16(gB0 + h * 32, s + d0);
    gld_lds16(gB1 + h * 32, s + d1);
  };

  // ---- fragment reads (swizzled chunk, identical pattern: 0 conflicts) ----
  const int chunk = (lq ^ ((lr >> 1) & 3)) * 8;
  const int ard = (wm + lr) * 32 + chunk;
  const int brd = (wn + lr) * 32 + chunk;

  f32x4 acc[8][4];
#pragma unroll
  for (int i = 0; i < 8; ++i)
#pragma unroll
    for (int j = 0; j < 4; ++j) acc[i][j] = (f32x4){0.f, 0.f, 0.f, 0.f};

  // double-buffered fragment registers (one-cluster-ahead prefetch)
  b16x8 av0[4], av1[4], bv0[4], bv1[4];
  auto rdA = [&](b16x8 (&dst)[4], int slot, int fb) {
#pragma unroll
    for (int i = 0; i < 4; ++i)
      dst[i] = *reinterpret_cast<const b16x8*>(sA + slot * 8192 + ard + (fb + i) * 512);
  };
  auto rdB = [&](b16x8 (&dst)[4], int slot) {
#pragma unroll
    for (int i = 0; i < 4; ++i)
      dst[i] = *reinterpret_cast<const b16x8*>(sB + slot * 8192 + brd + i * 512);
  };

  // Bias loaded & drained BEFORE staging: a stray VMEM op inside the loop
  // would shift the hand-counted vmcnt queue and break the schedule.
  float bval[4];
#pragma unroll
  for (int j = 0; j < 4; ++j) bval[j] = bias[n0 + wn + j * 16 + lr];
  WAIT_VM(0);

  // ---- prologue: 4 halves, wait(4), 3 more halves, wait(6) -----------------
  stageA(0); stageB(0); stageA(1); stageB(1);
  WAIT_VM(4);
  stageA(2); stageB(2); stageB(3);
  WAIT_VM(6);            // slots A0,B0,A1,B1 landed; {A2,B2,B3} in flight
  BARRIER();
  rdA(av0, 0, 0); rdB(bv0, 0);   // cluster (0,0) regs

  // ---- main loop: 31 iterations x 2 K-tiles x 4 phases --------------------
  // Phase: lgkmcnt(0) [prev-phase reads done]; [vmcnt]; barrier [block-wide
  // zero ds_reads in flight]; stage-issue; MFMA(cur); read(next).
  for (int u = 0; u < 31; ++u) {
    const int h = u * 4;
    // == tile halves h,h+1 (slots 0,1) ==
    WAIT_LGKM0();              BARRIER(); stageA(h + 3);
    MFMA16(av0, bv0, 0);       rdA(av1, 0, 4);
    WAIT_LGKM0(); WAIT_VM(6);  BARRIER(); stageB(h + 4);
    MFMA16(av1, bv0, 4);       rdA(av0, 1, 0); rdB(bv1, 1);
    WAIT_LGKM0();              BARRIER(); stageA(h + 4);
    MFMA16(av0, bv1, 0);       rdA(av1, 1, 4);
    WAIT_LGKM0(); WAIT_VM(6);  BARRIER(); stageB(h + 5);
    MFMA16(av1, bv1, 4);       rdA(av0, 2, 0); rdB(bv0, 2);
    // == tile halves h+2,h+3 (slots 2,3) ==
    WAIT_LGKM0();              BARRIER(); stageA(h + 5);
    MFMA16(av0, bv0, 0);       rdA(av1, 2, 4);
    WAIT_LGKM0(); WAIT_VM(6);  BARRIER(); stageB(h + 6);
    MFMA16(av1, bv0, 4);       rdA(av0, 3, 0); rdB(bv1, 3);
    WAIT_LGKM0();              BARRIER(); stageA(h + 6);
    MFMA16(av0, bv1, 0);       rdA(av1, 3, 4);
    WAIT_LGKM0(); WAIT_VM(6);  BARRIER(); stageB(h + 7);
    MFMA16(av1, bv1, 4);       rdA(av0, 0, 0); rdB(bv0, 0);
  }

  // ---- tail tile halves 124,125 (slots 0,1): last stage is A(127) ---------
  WAIT_LGKM0();              BARRIER(); stageA(127);
  MFMA16(av0, bv0, 0);       rdA(av1, 0, 4);
  WAIT_LGKM0(); WAIT_VM(6);  BARRIER();     // lands A125,B126
  MFMA16(av1, bv0, 4);       rdA(av0, 1, 0); rdB(bv1, 1);
  WAIT_LGKM0();              BARRIER();
  MFMA16(av0, bv1, 0);       rdA(av1, 1, 4);
  WAIT_LGKM0(); WAIT_VM(4);  BARRIER();     // lands A126
  MFMA16(av1, bv1, 4);       rdA(av0, 2, 0); rdB(bv0, 2);
  // ---- tail tile halves 126,127 (slots 2,3): no stages --------------------
  WAIT_LGKM0();              BARRIER();
  MFMA16(av0, bv0, 0);       rdA(av1, 2, 4);
  WAIT_LGKM0(); WAIT_VM(0);  BARRIER();     // drain: A127,B127 landed
  MFMA16(av1, bv0, 4);       rdA(av0, 3, 0); rdB(bv1, 3);
  WAIT_LGKM0();              BARRIER();
  MFMA16(av0, bv1, 0);       rdA(av1, 3, 4);
  WAIT_LGKM0();
  MFMA16(av1, bv1, 4);

  // ---- epilogue: C/D layout col=lane&15, row=(lane>>4)*4+reg --------------
#pragma unroll
  for (int j = 0; j < 4; ++j) {
    const int gn = n0 + wn + j * 16 + lr;
#pragma unroll
    for (int i = 0; i < 8; ++i) {
      const int gm = m0 + wm + i * 16 + lq * 4;
#pragma unroll
      for (int r = 0; r < 4; ++r) {
        float v = acc[i][j][r] + bval[j];
        out[(size_t)(gm + r) * Ndim + gn] = fast_tanh(v);
      }
    }
  }
}

// ---------------------------------------------------------------------------
extern "C" void kernel_launch(void* const* d_in, const int* in_sizes, int n_in,
                              void* d_out, int out_size, void* d_ws, size_t ws_size,
                              hipStream_t stream) {
  const float* x = (const float*)d_in[0];
  const float* W = (const float*)d_in[1];
  const float* b = (const float*)d_in[2];
  float* out = (float*)d_out;

  // ws layout: Wt bf16 [N*K] (16.8 MB) | feats bf16 [M*K] (134 MB)
  __bf16* Wt = (__bf16*)d_ws;
  __bf16* feats = Wt + (size_t)Ndim * Kdim;

  hipLaunchKernelGGL(feats_kernel, dim3(Mdim * Fdim / 8 / 256), dim3(256), 0,
                     stream, x, feats);
  hipLaunchKernelGGL(wtrans_kernel, dim3(Ndim / 32, Kdim / 32), dim3(32, 8), 0,
                     stream, W, Wt);
  hipLaunchKernelGGL(gemm_tanh_kernel, dim3(Ndim / 256, Mdim / 256), dim3(512),
                     0, stream, feats, Wt, b, out);
}